// Round 7
// baseline (1370.095 us; speedup 1.0000x reference)
//
#include <hip/hip_runtime.h>

#define NV 50000
#define NE 5000
#define NC 16
#define TAU_INV 2.0f
#define EPS 1e-8f

#define NCH 100         // v-chunks (part round-trip 67.6 MB)
#define VCH 500         // NV / NCH ; LDS slice = 500*32*4 = 62.5 KB (< 64 KB static)
#define GRP 2           // h-load ring depth (500 % 2 == 0) -- R0-proven
#define NXB 5           // x-blocks; 5 * 256 lanes * 4 edges = 5120 slots >= 5000
#define NBLK (NXB * NCH)   // 500
#define NLANE 5120
#define FB 80           // finale blocks: NLANE / 64

typedef float vf4 __attribute__((ext_vector_type(4)));
typedef float vf2 __attribute__((ext_vector_type(2)));

// ---------------- softmax: one thread per row, both pred_s and pred_t.
// Output layout: p[v][32] = [softmax(pred_s[v]) (16) | softmax(pred_t[v]) (16)]
// Thread (0,0) also zeroes the finale's 3 scalars (stream-ordered before finale).
__global__ __launch_bounds__(256) void softmax_kernel(
    const float* __restrict__ pred_s, const float* __restrict__ pred_t,
    float* __restrict__ p, float* __restrict__ scal) {
  int i = blockIdx.x * 256 + threadIdx.x;
  if (i == 0) { scal[0] = 0.f; scal[1] = 0.f; scal[2] = 0.f; }  // num, cnt, ticket
  if (i >= 2 * NV) return;
  const float* src;
  float* dst;
  if (i < NV) { src = pred_s + (size_t)i * NC; dst = p + (size_t)i * 32; }
  else        { int j = i - NV; src = pred_t + (size_t)j * NC; dst = p + (size_t)j * 32 + 16; }
  float4 a = ((const float4*)src)[0];
  float4 b = ((const float4*)src)[1];
  float4 c = ((const float4*)src)[2];
  float4 d = ((const float4*)src)[3];
  float x[16] = {a.x,a.y,a.z,a.w, b.x,b.y,b.z,b.w, c.x,c.y,c.z,c.w, d.x,d.y,d.z,d.w};
  float mx = x[0];
#pragma unroll
  for (int k = 1; k < 16; ++k) mx = fmaxf(mx, x[k]);
  float sum = 0.f;
#pragma unroll
  for (int k = 0; k < 16; ++k) { x[k] = expf(x[k] - mx); sum += x[k]; }
  float inv = 1.f / sum;
#pragma unroll
  for (int k = 0; k < 16; ++k) x[k] *= inv;
  float4 o0 = {x[0], x[1], x[2], x[3]};
  float4 o1 = {x[4], x[5], x[6], x[7]};
  float4 o2 = {x[8], x[9], x[10], x[11]};
  float4 o3 = {x[12], x[13], x[14], x[15]};
  ((float4*)dst)[0] = o0;
  ((float4*)dst)[1] = o1;
  ((float4*)dst)[2] = o2;
  ((float4*)dst)[3] = o3;
}

// packed fp32 FMA: A.lo += H2.lo*S2.lo; A.hi += H2.hi*S2.hi  (2 FMAs / instr)
#define PKFMA(A, H2, S2) \
  asm("v_pk_fma_f32 %0, %1, %2, %0" : "+v"(A) : "v"(H2), "v"(S2));

// ---------------- main accumulation (R6 structure), 4 edges per lane,
// nontemporal H stream, XCD-slab swizzle, inner loop in v_pk_fma_f32.
// Accumulator layout: aS[e][j] = {k=2j, k=2j+1} for edge e (same chains as
// the scalar version, same order -> bitwise-identical partials).
// part layout: part[y][k][NLANE], k: 0..15 S, 16..31 T, 32 deg
__global__ __launch_bounds__(256) void accum_kernel(
    const float* __restrict__ H, const float* __restrict__ p,
    float* __restrict__ part) {
  __shared__ float lp[VCH * 32];   // 62.5 KB
  int b = blockIdx.x;
  // NBLK=500: blocks 0..495 swizzle bijectively (8 XCD slabs of 62), rest identity
  int item;
  if (b < 496) item = (b & 7) * 62 + (b >> 3);
  else         item = b;
  int xb = item % NXB;
  int y  = item / NXB;
  int e0 = 4 * (xb * 256 + (int)threadIdx.x);
  if (e0 > NE - 4) e0 = NE - 4;   // dup lanes write identical values: benign
  int v0 = y * VCH;

  // stage the p slice (contiguous 64 KB) into LDS, coalesced float4
  {
    const float4* __restrict__ src = (const float4*)(p + (size_t)v0 * 32);
    float4* dst = (float4*)lp;
    for (int i = threadIdx.x; i < VCH * 8; i += 256) dst[i] = src[i];
  }
  __syncthreads();

  vf2 aS[4][8], aT[4][8];   // [edge][k-pair] -> 128 VGPRs total
#pragma unroll
  for (int e = 0; e < 4; ++e)
#pragma unroll
    for (int j = 0; j < 8; ++j) {
      aS[e][j] = (vf2){0.f, 0.f};
      aT[e][j] = (vf2){0.f, 0.f};
    }
  float4 dg = make_float4(0.f, 0.f, 0.f, 0.f);

  const float* __restrict__ hp = H + (size_t)v0 * NE + e0;

  vf4 hc[GRP];
#pragma unroll
  for (int u = 0; u < GRP; ++u)
    hc[u] = __builtin_nontemporal_load((const vf4*)(hp + (size_t)u * NE));

  for (int vb = 0; vb < VCH; vb += GRP) {
    int nb = (vb + GRP < VCH) ? vb + GRP : vb;   // last iter: benign re-load
    vf4 hn[GRP];
#pragma unroll
    for (int u = 0; u < GRP; ++u)
      hn[u] = __builtin_nontemporal_load((const vf4*)(hp + (size_t)(nb + u) * NE));

#pragma unroll
    for (int u = 0; u < GRP; ++u) {
      const float4* __restrict__ r = (const float4*)(lp + (size_t)(vb + u) * 32);
      vf4 h = hc[u];
      dg.x += h.x; dg.y += h.y; dg.z += h.z; dg.w += h.w;
      vf2 hb[4];
      hb[0] = (vf2){h.x, h.x};
      hb[1] = (vf2){h.y, h.y};
      hb[2] = (vf2){h.z, h.z};
      hb[3] = (vf2){h.w, h.w};
      float4 s0 = r[0], s1 = r[1], s2 = r[2], s3 = r[3];
      vf2 sp[8] = {{s0.x,s0.y},{s0.z,s0.w},{s1.x,s1.y},{s1.z,s1.w},
                   {s2.x,s2.y},{s2.z,s2.w},{s3.x,s3.y},{s3.z,s3.w}};
      float4 t0 = r[4], t1 = r[5], t2 = r[6], t3 = r[7];
      vf2 tp[8] = {{t0.x,t0.y},{t0.z,t0.w},{t1.x,t1.y},{t1.z,t1.w},
                   {t2.x,t2.y},{t2.z,t2.w},{t3.x,t3.y},{t3.z,t3.w}};
#pragma unroll
      for (int j = 0; j < 8; ++j) {
#pragma unroll
        for (int e = 0; e < 4; ++e) {
          PKFMA(aS[e][j], hb[e], sp[j])
          PKFMA(aT[e][j], hb[e], tp[j])
        }
      }
    }
#pragma unroll
    for (int u = 0; u < GRP; ++u) hc[u] = hn[u];
  }

  float* op = part + (size_t)y * 33 * NLANE + e0;
#pragma unroll
  for (int k = 0; k < 16; ++k) {
    vf4 w = {aS[0][k >> 1][k & 1], aS[1][k >> 1][k & 1],
             aS[2][k >> 1][k & 1], aS[3][k >> 1][k & 1]};
    *(vf4*)(op + (size_t)k * NLANE) = w;
  }
#pragma unroll
  for (int k = 0; k < 16; ++k) {
    vf4 w = {aT[0][k >> 1][k & 1], aT[1][k >> 1][k & 1],
             aT[2][k >> 1][k & 1], aT[3][k >> 1][k & 1]};
    *(vf4*)(op + (size_t)(16 + k) * NLANE) = w;
  }
  {
    vf4 w = {dg.x, dg.y, dg.z, dg.w};
    *(vf4*)(op + (size_t)32 * NLANE) = w;
  }
}

// ---------------- finale: fused y-reduction + per-edge KL + masked mean.
// Block b handles edges [b*64, b*64+64). 16 waves; wave yq accumulates
// y = yq, yq+16, ... (all 33 channels, coalesced 256B per load), LDS-combine,
// wave 0 computes KL, atomics + ticket: last block writes out.
__global__ __launch_bounds__(1024) void finale_kernel(
    const float* __restrict__ part, const unsigned char* __restrict__ e_mask,
    float* __restrict__ scal, float* __restrict__ out) {
  __shared__ float sl[33 * 64];
  int t = threadIdx.x;
  int el = t & 63, yq = t >> 6;          // wave index == yq (0..15)
  int e = blockIdx.x * 64 + el;

  float a[33];
#pragma unroll
  for (int k = 0; k < 33; ++k) a[k] = 0.f;
  for (int y = yq; y < NCH; y += 16) {
    const float* __restrict__ bp = part + (size_t)y * 33 * NLANE + e;
#pragma unroll
    for (int k = 0; k < 33; ++k) a[k] += bp[(size_t)k * NLANE];
  }

  for (int i = t; i < 33 * 64; i += 1024) sl[i] = 0.f;
  __syncthreads();
#pragma unroll
  for (int k = 0; k < 33; ++k) atomicAdd(&sl[k * 64 + el], a[k]);
  __syncthreads();

  if (t < 64) {   // wave 0: one edge per lane
    float num = 0.f, cntv = 0.f;
    if (e < NE && e_mask[e]) {
      float deg = sl[32 * 64 + el];
      float invd = 1.f / deg;
      float kl = 0.f;
#pragma unroll
      for (int k = 0; k < 16; ++k) {
        float ms = sl[k * 64 + el] * invd;
        float mt = sl[(16 + k) * 64 + el] * invd;
        float xs = ms * TAU_INV + EPS;
        float xt = mt * TAU_INV + EPS;
        kl += xt * (logf(xt) - logf(xs));
      }
      num = kl; cntv = 1.f;
    }
#pragma unroll
    for (int off = 32; off > 0; off >>= 1) {
      num += __shfl_down(num, off, 64);
      cntv += __shfl_down(cntv, off, 64);
    }
    if (t == 0) {
      atomicAdd(&scal[0], num);
      atomicAdd(&scal[1], cntv);
      __threadfence();
      unsigned int tk = atomicAdd((unsigned int*)&scal[2], 1u);
      if (tk == FB - 1) {
        float n = atomicAdd(&scal[0], 0.f);   // atomic read at coherent point
        float c = atomicAdd(&scal[1], 0.f);
        out[0] = n / fmaxf(c, 1.f);
      }
    }
  }
}

extern "C" void kernel_launch(void* const* d_in, const int* in_sizes, int n_in,
                              void* d_out, int out_size, void* d_ws, size_t ws_size,
                              hipStream_t stream) {
  const float* pred_s = (const float*)d_in[0];
  const float* pred_t = (const float*)d_in[1];
  const float* H      = (const float*)d_in[2];
  const unsigned char* e_mask = (const unsigned char*)d_in[3];

  float* ws   = (float*)d_ws;
  float* p    = ws;                                    // NV*32         (6.40 MB)
  float* part = p + (size_t)NV * 32;                   // NCH*33*NLANE  (67.6 MB)
  float* scal = part + (size_t)NCH * 33 * NLANE;       // 3 floats (num, cnt, ticket)

  softmax_kernel<<<dim3((2 * NV + 255) / 256), 256, 0, stream>>>(pred_s, pred_t, p, scal);
  accum_kernel<<<dim3(NBLK), 256, 0, stream>>>(H, p, part);
  finale_kernel<<<dim3(FB), 1024, 0, stream>>>(part, e_mask, scal, (float*)d_out);
}

// Round 8
// 1349.579 us; speedup vs baseline: 1.0152x; 1.0152x over previous
//
#include <hip/hip_runtime.h>

#define NV 50000
#define NE 5000
#define NC 16
#define TAU_INV 2.0f
#define EPS 1e-8f

#define NCH 100         // v-chunks (part round-trip 67.6 MB)
#define VCH 500         // NV / NCH ; LDS slice = 500*32*4 = 62.5 KB (< 64 KB static)
#define GRP 2           // h-load ring depth (500 % 2 == 0) -- R0-proven
#define NXB 5           // x-blocks; 5 * 256 lanes * 4 edges = 5120 slots >= 5000
#define NBLK (NXB * NCH)   // 500
#define NLANE 5120
#define FB 80           // finale blocks: NLANE / 64

typedef float vf4 __attribute__((ext_vector_type(4)));

// ---------------- softmax: one thread per row, both pred_s and pred_t.
// Output layout: p[v][32] = [softmax(pred_s[v]) (16) | softmax(pred_t[v]) (16)]
// Thread (0,0) also zeroes the finale's 3 scalars (stream-ordered before finale).
__global__ __launch_bounds__(256) void softmax_kernel(
    const float* __restrict__ pred_s, const float* __restrict__ pred_t,
    float* __restrict__ p, float* __restrict__ scal) {
  int i = blockIdx.x * 256 + threadIdx.x;
  if (i == 0) { scal[0] = 0.f; scal[1] = 0.f; scal[2] = 0.f; }  // num, cnt, ticket
  if (i >= 2 * NV) return;
  const float* src;
  float* dst;
  if (i < NV) { src = pred_s + (size_t)i * NC; dst = p + (size_t)i * 32; }
  else        { int j = i - NV; src = pred_t + (size_t)j * NC; dst = p + (size_t)j * 32 + 16; }
  float4 a = ((const float4*)src)[0];
  float4 b = ((const float4*)src)[1];
  float4 c = ((const float4*)src)[2];
  float4 d = ((const float4*)src)[3];
  float x[16] = {a.x,a.y,a.z,a.w, b.x,b.y,b.z,b.w, c.x,c.y,c.z,c.w, d.x,d.y,d.z,d.w};
  float mx = x[0];
#pragma unroll
  for (int k = 1; k < 16; ++k) mx = fmaxf(mx, x[k]);
  float sum = 0.f;
#pragma unroll
  for (int k = 0; k < 16; ++k) { x[k] = expf(x[k] - mx); sum += x[k]; }
  float inv = 1.f / sum;
#pragma unroll
  for (int k = 0; k < 16; ++k) x[k] *= inv;
  float4 o0 = {x[0], x[1], x[2], x[3]};
  float4 o1 = {x[4], x[5], x[6], x[7]};
  float4 o2 = {x[8], x[9], x[10], x[11]};
  float4 o3 = {x[12], x[13], x[14], x[15]};
  ((float4*)dst)[0] = o0;
  ((float4*)dst)[1] = o1;
  ((float4*)dst)[2] = o2;
  ((float4*)dst)[3] = o3;
}

// ---------------- main accumulation (R0-proven structure), 4 edges per lane,
// nontemporal H stream, XCD-slab swizzle. Part stores are NORMAL (L3-resident
// for finale). part layout: part[y][k][NLANE], k: 0..15 S, 16..31 T, 32 deg
__global__ __launch_bounds__(256) void accum_kernel(
    const float* __restrict__ H, const float* __restrict__ p,
    float* __restrict__ part) {
  __shared__ float lp[VCH * 32];   // 62.5 KB
  int b = blockIdx.x;
  // NBLK=500: blocks 0..495 swizzle bijectively (8 XCD slabs of 62), rest identity
  int item;
  if (b < 496) item = (b & 7) * 62 + (b >> 3);
  else         item = b;
  int xb = item % NXB;
  int y  = item / NXB;
  int e0 = 4 * (xb * 256 + (int)threadIdx.x);
  if (e0 > NE - 4) e0 = NE - 4;   // dup lanes write identical values: benign
  int v0 = y * VCH;

  // stage the p slice (contiguous 64 KB) into LDS, coalesced float4
  {
    const float4* __restrict__ src = (const float4*)(p + (size_t)v0 * 32);
    float4* dst = (float4*)lp;
    for (int i = threadIdx.x; i < VCH * 8; i += 256) dst[i] = src[i];
  }
  __syncthreads();

  float4 aS[16], aT[16], dg;
#pragma unroll
  for (int k = 0; k < 16; ++k) {
    aS[k] = make_float4(0.f, 0.f, 0.f, 0.f);
    aT[k] = make_float4(0.f, 0.f, 0.f, 0.f);
  }
  dg = make_float4(0.f, 0.f, 0.f, 0.f);

  const float* __restrict__ hp = H + (size_t)v0 * NE + e0;

  vf4 hc[GRP];
#pragma unroll
  for (int u = 0; u < GRP; ++u)
    hc[u] = __builtin_nontemporal_load((const vf4*)(hp + (size_t)u * NE));

  for (int vb = 0; vb < VCH; vb += GRP) {
    int nb = (vb + GRP < VCH) ? vb + GRP : vb;   // last iter: benign re-load
    vf4 hn[GRP];
#pragma unroll
    for (int u = 0; u < GRP; ++u)
      hn[u] = __builtin_nontemporal_load((const vf4*)(hp + (size_t)(nb + u) * NE));

#pragma unroll
    for (int u = 0; u < GRP; ++u) {
      const float4* __restrict__ r = (const float4*)(lp + (size_t)(vb + u) * 32);
      vf4 h = hc[u];
      dg.x += h.x; dg.y += h.y; dg.z += h.z; dg.w += h.w;
      {
        float4 s0 = r[0], s1 = r[1], s2 = r[2], s3 = r[3];
        float sv[16] = {s0.x,s0.y,s0.z,s0.w, s1.x,s1.y,s1.z,s1.w,
                        s2.x,s2.y,s2.z,s2.w, s3.x,s3.y,s3.z,s3.w};
#pragma unroll
        for (int k = 0; k < 16; ++k) {
          aS[k].x = fmaf(h.x, sv[k], aS[k].x);
          aS[k].y = fmaf(h.y, sv[k], aS[k].y);
          aS[k].z = fmaf(h.z, sv[k], aS[k].z);
          aS[k].w = fmaf(h.w, sv[k], aS[k].w);
        }
      }
      {
        float4 t0 = r[4], t1 = r[5], t2 = r[6], t3 = r[7];
        float tv[16] = {t0.x,t0.y,t0.z,t0.w, t1.x,t1.y,t1.z,t1.w,
                        t2.x,t2.y,t2.z,t2.w, t3.x,t3.y,t3.z,t3.w};
#pragma unroll
        for (int k = 0; k < 16; ++k) {
          aT[k].x = fmaf(h.x, tv[k], aT[k].x);
          aT[k].y = fmaf(h.y, tv[k], aT[k].y);
          aT[k].z = fmaf(h.z, tv[k], aT[k].z);
          aT[k].w = fmaf(h.w, tv[k], aT[k].w);
        }
      }
    }
#pragma unroll
    for (int u = 0; u < GRP; ++u) hc[u] = hn[u];
  }

  float* op = part + (size_t)y * 33 * NLANE + e0;
#pragma unroll
  for (int k = 0; k < 16; ++k) {
    vf4 w = {aS[k].x, aS[k].y, aS[k].z, aS[k].w};
    *(vf4*)(op + (size_t)k * NLANE) = w;
  }
#pragma unroll
  for (int k = 0; k < 16; ++k) {
    vf4 w = {aT[k].x, aT[k].y, aT[k].z, aT[k].w};
    *(vf4*)(op + (size_t)(16 + k) * NLANE) = w;
  }
  {
    vf4 w = {dg.x, dg.y, dg.z, dg.w};
    *(vf4*)(op + (size_t)32 * NLANE) = w;
  }
}

// ---------------- finale: fused y-reduction + per-edge KL + masked mean.
// Block b handles edges [b*64, b*64+64). 16 waves; wave yq accumulates
// y = yq, yq+16, ... (all 33 channels, coalesced 256B per load), LDS-combine,
// wave 0 computes KL, atomics + ticket: last block writes out.
__global__ __launch_bounds__(1024) void finale_kernel(
    const float* __restrict__ part, const unsigned char* __restrict__ e_mask,
    float* __restrict__ scal, float* __restrict__ out) {
  __shared__ float sl[33 * 64];
  int t = threadIdx.x;
  int el = t & 63, yq = t >> 6;          // wave index == yq (0..15)
  int e = blockIdx.x * 64 + el;

  float a[33];
#pragma unroll
  for (int k = 0; k < 33; ++k) a[k] = 0.f;
  for (int y = yq; y < NCH; y += 16) {
    const float* __restrict__ bp = part + (size_t)y * 33 * NLANE + e;
#pragma unroll
    for (int k = 0; k < 33; ++k) a[k] += bp[(size_t)k * NLANE];
  }

  for (int i = t; i < 33 * 64; i += 1024) sl[i] = 0.f;
  __syncthreads();
#pragma unroll
  for (int k = 0; k < 33; ++k) atomicAdd(&sl[k * 64 + el], a[k]);
  __syncthreads();

  if (t < 64) {   // wave 0: one edge per lane
    float num = 0.f, cntv = 0.f;
    if (e < NE && e_mask[e]) {
      float deg = sl[32 * 64 + el];
      float invd = 1.f / deg;
      float kl = 0.f;
#pragma unroll
      for (int k = 0; k < 16; ++k) {
        float ms = sl[k * 64 + el] * invd;
        float mt = sl[(16 + k) * 64 + el] * invd;
        float xs = ms * TAU_INV + EPS;
        float xt = mt * TAU_INV + EPS;
        kl += xt * (logf(xt) - logf(xs));
      }
      num = kl; cntv = 1.f;
    }
#pragma unroll
    for (int off = 32; off > 0; off >>= 1) {
      num += __shfl_down(num, off, 64);
      cntv += __shfl_down(cntv, off, 64);
    }
    if (t == 0) {
      atomicAdd(&scal[0], num);
      atomicAdd(&scal[1], cntv);
      __threadfence();
      unsigned int tk = atomicAdd((unsigned int*)&scal[2], 1u);
      if (tk == FB - 1) {
        float n = atomicAdd(&scal[0], 0.f);   // atomic read at coherent point
        float c = atomicAdd(&scal[1], 0.f);
        out[0] = n / fmaxf(c, 1.f);
      }
    }
  }
}

extern "C" void kernel_launch(void* const* d_in, const int* in_sizes, int n_in,
                              void* d_out, int out_size, void* d_ws, size_t ws_size,
                              hipStream_t stream) {
  const float* pred_s = (const float*)d_in[0];
  const float* pred_t = (const float*)d_in[1];
  const float* H      = (const float*)d_in[2];
  const unsigned char* e_mask = (const unsigned char*)d_in[3];

  float* ws   = (float*)d_ws;
  float* p    = ws;                                    // NV*32         (6.40 MB)
  float* part = p + (size_t)NV * 32;                   // NCH*33*NLANE  (67.6 MB)
  float* scal = part + (size_t)NCH * 33 * NLANE;       // 3 floats (num, cnt, ticket)

  softmax_kernel<<<dim3((2 * NV + 255) / 256), 256, 0, stream>>>(pred_s, pred_t, p, scal);
  accum_kernel<<<dim3(NBLK), 256, 0, stream>>>(H, p, part);
  finale_kernel<<<dim3(FB), 1024, 0, stream>>>(part, e_mask, scal, (float*)d_out);
}